// Round 4
// baseline (330.769 us; speedup 1.0000x reference)
//
#include <hip/hip_runtime.h>
#include <hip/hip_bf16.h>

// RelAttnBlock on MI355X (gfx950). fp32 I/O, bf16 MFMA core.
// B=8, L=1024, EMB=512, H=8, HD=64, BS=1024, M=8192.
//
// R4: attn rebuilt barrier-free:
//  - K/V/Er MFMA B-frags loaded directly from global (coalesced b128/lane),
//    no LDS staging, no __syncthreads in the kt loop.
//  - no-max softmax (shift-invariant; scores bounded ~|50| << fp32 exp range):
//    removes per-kt shuffle reductions + alpha rescale; single l-reduction at end.
//  - wave-private bias_s (stride 83 f32) and Ps (stride 68 bf16) chosen for
//    2-lanes/bank (free) LDS patterns.

typedef __bf16 bf16;
typedef __bf16 bf16x8 __attribute__((ext_vector_type(8)));
typedef float floatx4 __attribute__((ext_vector_type(4)));
typedef float f32x4 __attribute__((ext_vector_type(4)));

#define MFMA16 __builtin_amdgcn_mfma_f32_16x16x32_bf16

#define GS 40   // padded stride for 32-col bf16 GEMM tiles
#define BSS 83  // bias_s stride (f32 words): 4*82 % 32 == 8 -> gather-free
#define PSS 68  // Ps stride (bf16): 34 words, 4*34 % 32 == 8 -> free both ways

// ---- prep (weights transpose+cvt, Er cvt) + LayerNorm, one dispatch ----
__global__ __launch_bounds__(256) void prep_ln_kernel(
    const float* __restrict__ Wq, const float* __restrict__ Wk,
    const float* __restrict__ Wv, const float* __restrict__ Wo,
    const float* __restrict__ Er,
    const float* __restrict__ x, const float* __restrict__ g,
    const float* __restrict__ bvec,
    bf16* __restrict__ wt, bf16* __restrict__ er_b, bf16* __restrict__ h) {
  int blk = blockIdx.x;
  if (blk < 6144) {
    int idx = blk * 256 + threadIdx.x;
    if (idx < 4 * 512 * 512) {
      int w = idx >> 18;
      int r = idx & 262143;
      int n = r >> 9, k = r & 511;
      const float* W = (w == 0) ? Wq : (w == 1) ? Wk : (w == 2) ? Wv : Wo;
      wt[idx] = (bf16)W[k * 512 + n];            // wt[w][n][k] = W[k][n]
    } else {
      int e = idx - 4 * 512 * 512;               // 8*1024*64
      er_b[e] = (bf16)Er[e];
    }
    return;
  }
  int row = (blk - 6144) * 4 + (threadIdx.x >> 6);   // 8192 rows
  int lane = threadIdx.x & 63;
  const f32x4* xr = (const f32x4*)(x + row * 512 + lane * 8);
  f32x4 v0 = xr[0], v1 = xr[1];
  float f[8] = {v0[0], v0[1], v0[2], v0[3], v1[0], v1[1], v1[2], v1[3]};
  float s = 0.f, ss = 0.f;
#pragma unroll
  for (int i = 0; i < 8; i++) { s += f[i]; ss += f[i] * f[i]; }
#pragma unroll
  for (int m = 1; m < 64; m <<= 1) { s += __shfl_xor(s, m); ss += __shfl_xor(ss, m); }
  float mean = s * (1.0f / 512.0f);
  float var = ss * (1.0f / 512.0f) - mean * mean;
  float inv = rsqrtf(var + 1e-5f);
  const f32x4* gr = (const f32x4*)(g + lane * 8);
  const f32x4* br = (const f32x4*)(bvec + lane * 8);
  f32x4 g0 = gr[0], g1 = gr[1], b0 = br[0], b1 = br[1];
  float gg[8] = {g0[0], g0[1], g0[2], g0[3], g1[0], g1[1], g1[2], g1[3]};
  float bb[8] = {b0[0], b0[1], b0[2], b0[3], b1[0], b1[1], b1[2], b1[3]};
  bf16x8 o;
#pragma unroll
  for (int i = 0; i < 8; i++)
    o[i] = (bf16)((f[i] - mean) * inv * gg[i] + bb[i]);
  *(bf16x8*)(h + row * 512 + lane * 8) = o;
}

// C/D layout: col = lane&15, row = (lane>>4)*4 + reg.
// A layout: m = lane&15, k = (lane>>4)*8 + j.  B layout: n = lane&15, same k.

__global__ __launch_bounds__(256) void qkv_gemm(
    const bf16* __restrict__ A,      // h: 8192 x 512
    const bf16* __restrict__ wt,     // [3][512][512] n-major
    const float* __restrict__ bq, const float* __restrict__ bk,
    const float* __restrict__ bv,
    bf16* __restrict__ q_ws, bf16* __restrict__ k_ws, bf16* __restrict__ vt_ws) {
  __shared__ __align__(16) bf16 As[64 * GS];
  __shared__ __align__(16) bf16 Bs[64 * GS];
  int m0 = blockIdx.x * 64;
  int ng0 = blockIdx.y * 64;          // 0..1535
  int w = ng0 >> 9;                   // 0=Q 1=K 2=V
  int n0 = ng0 & 511;
  const bf16* Bt = wt + (w << 18);
  int tid = threadIdx.x;
  int wave = tid >> 6, lane = tid & 63, quad = lane >> 4, l16 = lane & 15;

  floatx4 acc[4] = {};
  for (int k0 = 0; k0 < 512; k0 += 32) {
    int r = tid >> 2, c = (tid & 3) * 8;
    *(bf16x8*)(As + r * GS + c) = *(const bf16x8*)(A + (m0 + r) * 512 + k0 + c);
    *(bf16x8*)(Bs + r * GS + c) = *(const bf16x8*)(Bt + (n0 + r) * 512 + k0 + c);
    __syncthreads();
    bf16x8 a = *(const bf16x8*)(As + (wave * 16 + l16) * GS + quad * 8);
#pragma unroll
    for (int nt = 0; nt < 4; nt++) {
      bf16x8 b = *(const bf16x8*)(Bs + (nt * 16 + l16) * GS + quad * 8);
      acc[nt] = MFMA16(a, b, acc[nt], 0, 0, 0);
    }
    __syncthreads();
  }

  const float* bias = (w == 0) ? bq : (w == 1) ? bk : bv;
#pragma unroll
  for (int nt = 0; nt < 4; nt++) {
    int col = n0 + nt * 16 + l16;
    float bb = bias[col];
    int hh = col >> 6, d = col & 63;
#pragma unroll
    for (int r = 0; r < 4; r++) {
      int mrow = m0 + wave * 16 + quad * 4 + r;
      int b_ = mrow >> 10, l = mrow & 1023;
      int bh = b_ * 8 + hh;
      float v = acc[nt][r] + bb;
      if (w == 0)       q_ws[(bh << 16) + (l << 6) + d] = (bf16)v;
      else if (w == 1)  k_ws[(bh << 16) + (l << 6) + d] = (bf16)(v * 0.125f);
      else              vt_ws[(bh << 16) + (d << 10) + l] = (bf16)v;
    }
  }
}

__global__ __launch_bounds__(256) void attn_kernel(
    const bf16* __restrict__ q_ws, const bf16* __restrict__ k_ws,
    const bf16* __restrict__ vt_ws, const bf16* __restrict__ Er,
    bf16* __restrict__ o_ws) {
  // wave-private LDS only; NO barriers in the kt loop.
  __shared__ __align__(16) float bias_s[4][16 * BSS];   // 16 x 80 (+3 pad)
  __shared__ __align__(16) bf16 Ps[4][16 * PSS];        // 16 x 64 (+4 pad)

  int qt = blockIdx.x;       // 0..15
  int bh = blockIdx.y;       // 0..63
  int hh = bh & 7;
  int l0 = qt * 64;
  int tid = threadIdx.x, wave = tid >> 6, lane = tid & 63;
  int quad = lane >> 4, l16 = lane & 15;

  // Persistent Q A-fragments for this wave's 16-row strip.
  const bf16* qbase = q_ws + (bh << 16) + ((l0 + wave * 16 + l16) << 6);
  bf16x8 aq0 = *(const bf16x8*)(qbase + quad * 8);
  bf16x8 aq1 = *(const bf16x8*)(qbase + 32 + quad * 8);

  const bf16* kbh = k_ws + (bh << 16);
  const bf16* vbh = vt_ws + (bh << 16);
  const bf16* ebh = Er + (hh << 16);
  float* bw = bias_s[wave];
  bf16* pw = Ps[wave];

  float l_run[4] = {0.f, 0.f, 0.f, 0.f};
  floatx4 acc_o[4] = {};

  // Wave w's bias cover: global cols [48-16w,128-16w) = tiles nt=3-w..7-w;
  // local gather col = 15 + dk - sdl (wave-invariant).
  int ebase = -l0 - 63 + (3 - wave) * 16 + l16 + 2048;

  for (int kt = 0; kt < 16; kt++) {
    int k0 = kt * 64;
    // ---- S = Q K'^T (scale folded into K'), B-frags direct from global ----
    floatx4 acc_s[4] = {};
#pragma unroll
    for (int nt = 0; nt < 4; nt++) {
      const bf16* kr = kbh + ((k0 + nt * 16 + l16) << 6) + quad * 8;
      bf16x8 b0 = *(const bf16x8*)kr;
      bf16x8 b1 = *(const bf16x8*)(kr + 32);
      acc_s[nt] = MFMA16(aq0, b0, acc_s[nt], 0, 0, 0);
      acc_s[nt] = MFMA16(aq1, b1, acc_s[nt], 0, 0, 0);
    }
    // ---- rel-bias 5-tile cover, Er frags direct from global ----
#pragma unroll
    for (int nt2 = 0; nt2 < 5; nt2++) {
      int grow = (ebase + k0 + nt2 * 16) & 1023;     // wrap mod 1024
      const bf16* er = ebh + (grow << 6) + quad * 8;
      bf16x8 b0 = *(const bf16x8*)er;
      bf16x8 b1 = *(const bf16x8*)(er + 32);
      floatx4 accb = {};
      accb = MFMA16(aq0, b0, accb, 0, 0, 0);
      accb = MFMA16(aq1, b1, accb, 0, 0, 0);
#pragma unroll
      for (int r = 0; r < 4; r++)
        bw[(quad * 4 + r) * BSS + nt2 * 16 + l16] = accb[r];
    }
    // ---- gather + exp (no max subtraction; shift-invariant, bounded) ----
    float pv[4][4];
#pragma unroll
    for (int nt = 0; nt < 4; nt++) {
      int dk = nt * 16 + l16;
#pragma unroll
      for (int r = 0; r < 4; r++) {
        int sdl = quad * 4 + r;
        float sc = acc_s[nt][r] + bw[sdl * BSS + 15 + dk - sdl];
        pv[nt][r] = __expf(sc);
      }
    }
#pragma unroll
    for (int r = 0; r < 4; r++)
      l_run[r] += pv[0][r] + pv[1][r] + pv[2][r] + pv[3][r];
    // ---- P: C-layout -> LDS -> A-layout (wave-private) ----
#pragma unroll
    for (int nt = 0; nt < 4; nt++)
#pragma unroll
      for (int r = 0; r < 4; r++)
        pw[(quad * 4 + r) * PSS + nt * 16 + l16] = (bf16)pv[nt][r];
    bf16x8 ap0 = *(const bf16x8*)(pw + l16 * PSS + quad * 8);
    bf16x8 ap1 = *(const bf16x8*)(pw + l16 * PSS + 32 + quad * 8);
    // ---- O += P V, V^T B-frags direct from global ----
#pragma unroll
    for (int dt = 0; dt < 4; dt++) {
      const bf16* vr = vbh + ((dt * 16 + l16) << 10) + k0 + quad * 8;
      bf16x8 b0 = *(const bf16x8*)vr;
      bf16x8 b1 = *(const bf16x8*)(vr + 32);
      acc_o[dt] = MFMA16(ap0, b0, acc_o[dt], 0, 0, 0);
      acc_o[dt] = MFMA16(ap1, b1, acc_o[dt], 0, 0, 0);
    }
  }

  // single deferred row-sum reduction over l16 (rows = quad*4+r)
#pragma unroll
  for (int r = 0; r < 4; r++) {
#pragma unroll
    for (int m = 1; m < 16; m <<= 1) l_run[r] += __shfl_xor(l_run[r], m);
  }
  float invl[4];
#pragma unroll
  for (int r = 0; r < 4; r++) invl[r] = 1.0f / l_run[r];
#pragma unroll
  for (int dt = 0; dt < 4; dt++) {
    int col = (hh << 6) + dt * 16 + l16;
#pragma unroll
    for (int r = 0; r < 4; r++) {
      int row = ((bh >> 3) << 10) + l0 + wave * 16 + quad * 4 + r;
      o_ws[row * 512 + col] = (bf16)(acc_o[dt][r] * invl[r]);
    }
  }
}

__global__ __launch_bounds__(256) void out_gemm(
    const bf16* __restrict__ A,      // o_ws: 8192 x 512
    const bf16* __restrict__ Bt,     // WoT n-major
    const float* __restrict__ bo, float* __restrict__ out) {
  __shared__ __align__(16) bf16 As[64 * GS];
  __shared__ __align__(16) bf16 Bs[64 * GS];
  int m0 = blockIdx.x * 64;
  int n0 = blockIdx.y * 64;
  int tid = threadIdx.x;
  int wave = tid >> 6, lane = tid & 63, quad = lane >> 4, l16 = lane & 15;

  floatx4 acc[4] = {};
  for (int k0 = 0; k0 < 512; k0 += 32) {
    int r = tid >> 2, c = (tid & 3) * 8;
    *(bf16x8*)(As + r * GS + c) = *(const bf16x8*)(A + (m0 + r) * 512 + k0 + c);
    *(bf16x8*)(Bs + r * GS + c) = *(const bf16x8*)(Bt + (n0 + r) * 512 + k0 + c);
    __syncthreads();
    bf16x8 a = *(const bf16x8*)(As + (wave * 16 + l16) * GS + quad * 8);
#pragma unroll
    for (int nt = 0; nt < 4; nt++) {
      bf16x8 b = *(const bf16x8*)(Bs + (nt * 16 + l16) * GS + quad * 8);
      acc[nt] = MFMA16(a, b, acc[nt], 0, 0, 0);
    }
    __syncthreads();
  }
#pragma unroll
  for (int nt = 0; nt < 4; nt++) {
    int col = n0 + nt * 16 + l16;
    float bb = bo[col];
#pragma unroll
    for (int r = 0; r < 4; r++) {
      int mrow = m0 + wave * 16 + quad * 4 + r;
      out[mrow * 512 + col] = acc[nt][r] + bb;
    }
  }
}

extern "C" void kernel_launch(void* const* d_in, const int* in_sizes, int n_in,
                              void* d_out, int out_size, void* d_ws, size_t ws_size,
                              hipStream_t stream) {
  const float* x    = (const float*)d_in[0];
  const float* ln_g = (const float*)d_in[1];
  const float* ln_b = (const float*)d_in[2];
  const float* Wq   = (const float*)d_in[3];
  const float* bq   = (const float*)d_in[4];
  const float* Wk   = (const float*)d_in[5];
  const float* bk   = (const float*)d_in[6];
  const float* Wv   = (const float*)d_in[7];
  const float* bv   = (const float*)d_in[8];
  const float* Wo   = (const float*)d_in[9];
  const float* bo   = (const float*)d_in[10];
  const float* Er   = (const float*)d_in[11];
  float* out = (float*)d_out;

  char* ws = (char*)d_ws;
  bf16* wt    = (bf16*)(ws);                       // 2MB: [4][512][512]
  bf16* er_b  = (bf16*)(ws + (2u << 20));          // 1MB
  bf16* h     = (bf16*)(ws + (3u << 20));          // 8MB
  bf16* o_ws  = h;                                 // alias
  bf16* q_ws  = (bf16*)(ws + (11u << 20));         // 8MB
  bf16* k_ws  = (bf16*)(ws + (19u << 20));         // 8MB
  bf16* vt_ws = (bf16*)(ws + (27u << 20));         // 8MB

  prep_ln_kernel<<<8192, 256, 0, stream>>>(Wq, Wk, Wv, Wo, Er, x, ln_g, ln_b,
                                           wt, er_b, h);
  qkv_gemm<<<dim3(128, 24), 256, 0, stream>>>(h, wt, bq, bk, bv, q_ws, k_ws, vt_ws);
  attn_kernel<<<dim3(16, 64), 256, 0, stream>>>(q_ws, k_ws, vt_ws, er_b, o_ws);
  out_gemm<<<dim3(128, 8), 256, 0, stream>>>(o_ws, wt + 3 * 262144, bo, out);
}

// Round 5
// 216.614 us; speedup vs baseline: 1.5270x; 1.5270x over previous
//
#include <hip/hip_runtime.h>
#include <hip/hip_bf16.h>

// RelAttnBlock on MI355X (gfx950). fp32 I/O, bf16 MFMA core.
// B=8, L=1024, EMB=512, H=8, HD=64, BS=1024, M=8192.
//
// R5: attn = R3 staging structure + 128-row Q tiles (2 strips/wave, staged
//     K/V/Er amortized 2x, K/V frags hoisted & shared across strips) +
//     no-max softmax (R4-proven; bounded scores, shift-invariance exact).
//     2 barriers/kt. Grid 512 blocks = exactly 2/CU resident.
//     qkv/out GEMMs upgraded to 128x128 tiles (4-wave quadrants).

typedef __bf16 bf16;
typedef __bf16 bf16x8 __attribute__((ext_vector_type(8)));
typedef float floatx4 __attribute__((ext_vector_type(4)));
typedef float f32x4 __attribute__((ext_vector_type(4)));

#define MFMA16 __builtin_amdgcn_mfma_f32_16x16x32_bf16

#define KS 72   // stride for 64-col bf16 staging tiles (144B = 4-bank rotation)
#define BSS 83  // bias_s stride (f32): gather pattern lands 2 lanes/bank
#define PSS 68  // Ps stride (bf16)
#define GS 40   // stride for 32-col bf16 GEMM staging tiles

// ---- prep (weights transpose+cvt, Er cvt) + LayerNorm, one dispatch ----
__global__ __launch_bounds__(256) void prep_ln_kernel(
    const float* __restrict__ Wq, const float* __restrict__ Wk,
    const float* __restrict__ Wv, const float* __restrict__ Wo,
    const float* __restrict__ Er,
    const float* __restrict__ x, const float* __restrict__ g,
    const float* __restrict__ bvec,
    bf16* __restrict__ wt, bf16* __restrict__ er_b, bf16* __restrict__ h) {
  int blk = blockIdx.x;
  if (blk < 6144) {
    int idx = blk * 256 + threadIdx.x;
    if (idx < 4 * 512 * 512) {
      int w = idx >> 18;
      int r = idx & 262143;
      int n = r >> 9, k = r & 511;
      const float* W = (w == 0) ? Wq : (w == 1) ? Wk : (w == 2) ? Wv : Wo;
      wt[idx] = (bf16)W[k * 512 + n];            // wt[w][n][k] = W[k][n]
    } else {
      int e = idx - 4 * 512 * 512;               // 8*1024*64
      er_b[e] = (bf16)Er[e];
    }
    return;
  }
  int row = (blk - 6144) * 4 + (threadIdx.x >> 6);   // 8192 rows
  int lane = threadIdx.x & 63;
  const f32x4* xr = (const f32x4*)(x + row * 512 + lane * 8);
  f32x4 v0 = xr[0], v1 = xr[1];
  float f[8] = {v0[0], v0[1], v0[2], v0[3], v1[0], v1[1], v1[2], v1[3]};
  float s = 0.f, ss = 0.f;
#pragma unroll
  for (int i = 0; i < 8; i++) { s += f[i]; ss += f[i] * f[i]; }
#pragma unroll
  for (int m = 1; m < 64; m <<= 1) { s += __shfl_xor(s, m); ss += __shfl_xor(ss, m); }
  float mean = s * (1.0f / 512.0f);
  float var = ss * (1.0f / 512.0f) - mean * mean;
  float inv = rsqrtf(var + 1e-5f);
  const f32x4* gr = (const f32x4*)(g + lane * 8);
  const f32x4* br = (const f32x4*)(bvec + lane * 8);
  f32x4 g0 = gr[0], g1 = gr[1], b0 = br[0], b1 = br[1];
  float gg[8] = {g0[0], g0[1], g0[2], g0[3], g1[0], g1[1], g1[2], g1[3]};
  float bb[8] = {b0[0], b0[1], b0[2], b0[3], b1[0], b1[1], b1[2], b1[3]};
  bf16x8 o;
#pragma unroll
  for (int i = 0; i < 8; i++)
    o[i] = (bf16)((f[i] - mean) * inv * gg[i] + bb[i]);
  *(bf16x8*)(h + row * 512 + lane * 8) = o;
}

// C/D layout: col = lane&15, row = (lane>>4)*4 + reg.
// A layout: m = lane&15, k = (lane>>4)*8 + j.  B layout: n = lane&15, same k.

__global__ __launch_bounds__(256) void qkv_gemm(
    const bf16* __restrict__ A,      // h: 8192 x 512
    const bf16* __restrict__ wt,     // [3][512][512] n-major
    const float* __restrict__ bq, const float* __restrict__ bk,
    const float* __restrict__ bv,
    bf16* __restrict__ q_ws, bf16* __restrict__ k_ws, bf16* __restrict__ vt_ws) {
  __shared__ __align__(16) bf16 As[128 * GS];
  __shared__ __align__(16) bf16 Bs[128 * GS];
  int m0 = blockIdx.x * 128;
  int ng0 = blockIdx.y * 128;         // 0..1408, within one 512-block
  int w = ng0 >> 9;                   // 0=Q 1=K 2=V (uniform per block)
  int n0 = ng0 & 511;
  const bf16* Bt = wt + (w << 18);
  int tid = threadIdx.x;
  int wave = tid >> 6, lane = tid & 63, quad = lane >> 4, l16 = lane & 15;
  int mq = (wave >> 1) * 64, nq = (wave & 1) * 64;

  floatx4 acc[4][4] = {};
  for (int k0 = 0; k0 < 512; k0 += 32) {
    int r = tid >> 1, c = (tid & 1) * 16;
    *(bf16x8*)(As + r * GS + c)     = *(const bf16x8*)(A + (m0 + r) * 512 + k0 + c);
    *(bf16x8*)(As + r * GS + c + 8) = *(const bf16x8*)(A + (m0 + r) * 512 + k0 + c + 8);
    *(bf16x8*)(Bs + r * GS + c)     = *(const bf16x8*)(Bt + (n0 + r) * 512 + k0 + c);
    *(bf16x8*)(Bs + r * GS + c + 8) = *(const bf16x8*)(Bt + (n0 + r) * 512 + k0 + c + 8);
    __syncthreads();
    bf16x8 a[4], b[4];
#pragma unroll
    for (int mt = 0; mt < 4; mt++)
      a[mt] = *(const bf16x8*)(As + (mq + mt * 16 + l16) * GS + quad * 8);
#pragma unroll
    for (int nt = 0; nt < 4; nt++)
      b[nt] = *(const bf16x8*)(Bs + (nq + nt * 16 + l16) * GS + quad * 8);
#pragma unroll
    for (int mt = 0; mt < 4; mt++)
#pragma unroll
      for (int nt = 0; nt < 4; nt++)
        acc[mt][nt] = MFMA16(a[mt], b[nt], acc[mt][nt], 0, 0, 0);
    __syncthreads();
  }

  const float* bias = (w == 0) ? bq : (w == 1) ? bk : bv;
#pragma unroll
  for (int nt = 0; nt < 4; nt++) {
    int col = n0 + nq + nt * 16 + l16;   // 0..511 within this W
    float bb = bias[col];
    int hh = col >> 6, d = col & 63;
#pragma unroll
    for (int mt = 0; mt < 4; mt++) {
#pragma unroll
      for (int r = 0; r < 4; r++) {
        int mrow = m0 + mq + mt * 16 + quad * 4 + r;   // 0..8191
        int b_ = mrow >> 10, l = mrow & 1023;
        int bh = b_ * 8 + hh;
        float v = acc[mt][nt][r] + bb;
        if (w == 0)       q_ws[(bh << 16) + (l << 6) + d] = (bf16)v;
        else if (w == 1)  k_ws[(bh << 16) + (l << 6) + d] = (bf16)(v * 0.125f);
        else              vt_ws[(bh << 16) + (d << 10) + l] = (bf16)v;
      }
    }
  }
}

__global__ __launch_bounds__(256, 2) void attn_kernel(
    const bf16* __restrict__ q_ws, const bf16* __restrict__ k_ws,
    const bf16* __restrict__ vt_ws, const bf16* __restrict__ Er,
    bf16* __restrict__ o_ws) {
  __shared__ __align__(16) bf16 Ks_s[64 * KS];          //  9.2 KB [key][d]
  __shared__ __align__(16) bf16 Vs[64 * KS];            //  9.2 KB [d][key]
  __shared__ __align__(16) bf16 Ers[192 * KS];          // 27.6 KB [cover r][d]
  __shared__ __align__(16) float bias_s[4][16 * BSS];   // 21.2 KB per-wave
  __shared__ __align__(16) bf16 Ps[4][16 * PSS];        //  8.7 KB per-wave

  int qt = blockIdx.x;       // 0..7 (128-row Q tiles)
  int bh = blockIdx.y;       // 0..63
  int hh = bh & 7;
  int l0 = qt << 7;
  int tid = threadIdx.x, wave = tid >> 6, lane = tid & 63;
  int quad = lane >> 4, l16 = lane & 15;

  // Two 16-row strips per wave: s = strip*64 + wave*16.
  bf16x8 aq0[2], aq1[2];
#pragma unroll
  for (int strip = 0; strip < 2; strip++) {
    const bf16* qb = q_ws + (bh << 16) + ((l0 + strip * 64 + wave * 16 + l16) << 6);
    aq0[strip] = *(const bf16x8*)(qb + quad * 8);
    aq1[strip] = *(const bf16x8*)(qb + 32 + quad * 8);
  }

  const bf16* kbh = k_ws + (bh << 16);
  const bf16* vbh = vt_ws + (bh << 16);
  const bf16* ebh = Er + (hh << 16);
  float* bw = bias_s[wave];
  bf16* pw = Ps[wave];

  float l_run[2][4] = {};
  floatx4 acc_o[2][4] = {};

  // Er cover: 192 rows, base = k0 - l0 - 127 (local col = 127 + dk - dl).
  int e0 = -l0 - 127 + 2048;

  for (int kt = 0; kt < 16; kt++) {
    int k0 = kt * 64;
    // ---- stage K', V^T (64x64 each), Er cover (192x64) ----
#pragma unroll
    for (int i = 0; i < 2; i++) {
      int o = tid + i * 256;            // 0..511
      int row = o >> 3, ch = (o & 7) * 8;
      *(bf16x8*)(Ks_s + row * KS + ch) =
          *(const bf16x8*)(kbh + ((k0 + row) << 6) + ch);
      *(bf16x8*)(Vs + row * KS + ch) =
          *(const bf16x8*)(vbh + (row << 10) + k0 + ch);
    }
#pragma unroll
    for (int i = 0; i < 6; i++) {
      int o = tid + i * 256;            // 0..1535
      int row = o >> 3, ch = (o & 7) * 8;
      int grow = (e0 + k0 + row) & 1023;
      *(bf16x8*)(Ers + row * KS + ch) =
          *(const bf16x8*)(ebh + (grow << 6) + ch);
    }
    __syncthreads();

    // ---- hoisted K/V B-fragments, shared by both strips ----
    bf16x8 kb0[4], kb1[4], vb0[4], vb1[4];
#pragma unroll
    for (int nt = 0; nt < 4; nt++) {
      const bf16* kr = Ks_s + (nt * 16 + l16) * KS + quad * 8;
      kb0[nt] = *(const bf16x8*)kr;
      kb1[nt] = *(const bf16x8*)(kr + 32);
      const bf16* vr = Vs + (nt * 16 + l16) * KS + quad * 8;
      vb0[nt] = *(const bf16x8*)vr;
      vb1[nt] = *(const bf16x8*)(vr + 32);
    }

#pragma unroll
    for (int strip = 0; strip < 2; strip++) {
      // ---- S = Q K'^T ----
      floatx4 acc_s[4] = {};
#pragma unroll
      for (int nt = 0; nt < 4; nt++) {
        acc_s[nt] = MFMA16(aq0[strip], kb0[nt], acc_s[nt], 0, 0, 0);
        acc_s[nt] = MFMA16(aq1[strip], kb1[nt], acc_s[nt], 0, 0, 0);
      }
      // ---- rel-bias 5-tile cover; strip window tiles t0..t0+4,
      //      local gather col = 15 + dk - sdl (wave/strip-invariant) ----
      int t0 = (strip ? 3 : 7) - wave;
#pragma unroll
      for (int nt2 = 0; nt2 < 5; nt2++) {
        int erow = (t0 + nt2) * 16 + l16;
        const bf16* er = Ers + erow * KS + quad * 8;
        bf16x8 b0 = *(const bf16x8*)er;
        bf16x8 b1 = *(const bf16x8*)(er + 32);
        floatx4 accb = {};
        accb = MFMA16(aq0[strip], b0, accb, 0, 0, 0);
        accb = MFMA16(aq1[strip], b1, accb, 0, 0, 0);
#pragma unroll
        for (int r = 0; r < 4; r++)
          bw[(quad * 4 + r) * BSS + nt2 * 16 + l16] = accb[r];
      }
      // ---- gather + exp (no max; shift-invariant, bounded) ----
      float pv[4][4];
#pragma unroll
      for (int nt = 0; nt < 4; nt++) {
        int dk = nt * 16 + l16;
#pragma unroll
        for (int r = 0; r < 4; r++) {
          int sdl = quad * 4 + r;
          float sc = acc_s[nt][r] + bw[sdl * BSS + 15 + dk - sdl];
          pv[nt][r] = __expf(sc);
        }
      }
#pragma unroll
      for (int r = 0; r < 4; r++)
        l_run[strip][r] += pv[0][r] + pv[1][r] + pv[2][r] + pv[3][r];
      // ---- P: C-layout -> LDS -> A-layout (wave-private, in-order DS) ----
#pragma unroll
      for (int nt = 0; nt < 4; nt++)
#pragma unroll
        for (int r = 0; r < 4; r++)
          pw[(quad * 4 + r) * PSS + nt * 16 + l16] = (bf16)pv[nt][r];
      bf16x8 ap0 = *(const bf16x8*)(pw + l16 * PSS + quad * 8);
      bf16x8 ap1 = *(const bf16x8*)(pw + l16 * PSS + 32 + quad * 8);
      // ---- O += P V ----
#pragma unroll
      for (int dt = 0; dt < 4; dt++) {
        acc_o[strip][dt] = MFMA16(ap0, vb0[dt], acc_o[strip][dt], 0, 0, 0);
        acc_o[strip][dt] = MFMA16(ap1, vb1[dt], acc_o[strip][dt], 0, 0, 0);
      }
    }
    __syncthreads();   // protect Ks/Vs/Ers restage next kt
  }

  // deferred row-sum reduction + normalize + store
#pragma unroll
  for (int strip = 0; strip < 2; strip++) {
    float invl[4];
#pragma unroll
    for (int r = 0; r < 4; r++) {
      float lr = l_run[strip][r];
#pragma unroll
      for (int m = 1; m < 16; m <<= 1) lr += __shfl_xor(lr, m);
      invl[r] = 1.0f / lr;
    }
#pragma unroll
    for (int dt = 0; dt < 4; dt++) {
      int col = (hh << 6) + dt * 16 + l16;
#pragma unroll
      for (int r = 0; r < 4; r++) {
        int row = ((bh >> 3) << 10) + l0 + strip * 64 + wave * 16 + quad * 4 + r;
        o_ws[row * 512 + col] = (bf16)(acc_o[strip][dt][r] * invl[r]);
      }
    }
  }
}

__global__ __launch_bounds__(256) void out_gemm(
    const bf16* __restrict__ A,      // o_ws: 8192 x 512
    const bf16* __restrict__ Bt,     // WoT n-major
    const float* __restrict__ bo, float* __restrict__ out) {
  __shared__ __align__(16) bf16 As[128 * GS];
  __shared__ __align__(16) bf16 Bs[128 * GS];
  int m0 = blockIdx.x * 128;
  int n0 = blockIdx.y * 128;
  int tid = threadIdx.x;
  int wave = tid >> 6, lane = tid & 63, quad = lane >> 4, l16 = lane & 15;
  int mq = (wave >> 1) * 64, nq = (wave & 1) * 64;

  floatx4 acc[4][4] = {};
  for (int k0 = 0; k0 < 512; k0 += 32) {
    int r = tid >> 1, c = (tid & 1) * 16;
    *(bf16x8*)(As + r * GS + c)     = *(const bf16x8*)(A + (m0 + r) * 512 + k0 + c);
    *(bf16x8*)(As + r * GS + c + 8) = *(const bf16x8*)(A + (m0 + r) * 512 + k0 + c + 8);
    *(bf16x8*)(Bs + r * GS + c)     = *(const bf16x8*)(Bt + (n0 + r) * 512 + k0 + c);
    *(bf16x8*)(Bs + r * GS + c + 8) = *(const bf16x8*)(Bt + (n0 + r) * 512 + k0 + c + 8);
    __syncthreads();
    bf16x8 a[4], b[4];
#pragma unroll
    for (int mt = 0; mt < 4; mt++)
      a[mt] = *(const bf16x8*)(As + (mq + mt * 16 + l16) * GS + quad * 8);
#pragma unroll
    for (int nt = 0; nt < 4; nt++)
      b[nt] = *(const bf16x8*)(Bs + (nq + nt * 16 + l16) * GS + quad * 8);
#pragma unroll
    for (int mt = 0; mt < 4; mt++)
#pragma unroll
      for (int nt = 0; nt < 4; nt++)
        acc[mt][nt] = MFMA16(a[mt], b[nt], acc[mt][nt], 0, 0, 0);
    __syncthreads();
  }
#pragma unroll
  for (int nt = 0; nt < 4; nt++) {
    int col = n0 + nq + nt * 16 + l16;
    float bb = bo[col];
#pragma unroll
    for (int mt = 0; mt < 4; mt++) {
#pragma unroll
      for (int r = 0; r < 4; r++) {
        int mrow = m0 + mq + mt * 16 + quad * 4 + r;
        out[mrow * 512 + col] = acc[mt][nt][r] + bb;
      }
    }
  }
}

extern "C" void kernel_launch(void* const* d_in, const int* in_sizes, int n_in,
                              void* d_out, int out_size, void* d_ws, size_t ws_size,
                              hipStream_t stream) {
  const float* x    = (const float*)d_in[0];
  const float* ln_g = (const float*)d_in[1];
  const float* ln_b = (const float*)d_in[2];
  const float* Wq   = (const float*)d_in[3];
  const float* bq   = (const float*)d_in[4];
  const float* Wk   = (const float*)d_in[5];
  const float* bk   = (const float*)d_in[6];
  const float* Wv   = (const float*)d_in[7];
  const float* bv   = (const float*)d_in[8];
  const float* Wo   = (const float*)d_in[9];
  const float* bo   = (const float*)d_in[10];
  const float* Er   = (const float*)d_in[11];
  float* out = (float*)d_out;

  char* ws = (char*)d_ws;
  bf16* wt    = (bf16*)(ws);                       // 2MB: [4][512][512]
  bf16* er_b  = (bf16*)(ws + (2u << 20));          // 1MB
  bf16* h     = (bf16*)(ws + (3u << 20));          // 8MB
  bf16* o_ws  = h;                                 // alias (h dead by then)
  bf16* q_ws  = (bf16*)(ws + (11u << 20));         // 8MB
  bf16* k_ws  = (bf16*)(ws + (19u << 20));         // 8MB
  bf16* vt_ws = (bf16*)(ws + (27u << 20));         // 8MB

  prep_ln_kernel<<<8192, 256, 0, stream>>>(Wq, Wk, Wv, Wo, Er, x, ln_g, ln_b,
                                           wt, er_b, h);
  qkv_gemm<<<dim3(64, 12), 256, 0, stream>>>(h, wt, bq, bk, bv, q_ws, k_ws, vt_ws);
  attn_kernel<<<dim3(8, 64), 256, 0, stream>>>(q_ws, k_ws, vt_ws, er_b, o_ws);
  out_gemm<<<dim3(64, 4), 256, 0, stream>>>(o_ws, wt + 3 * 262144, bo, out);
}